// Round 1
// baseline (86.512 us; speedup 1.0000x reference)
//
#include <hip/hip_runtime.h>

#define DD 512
#define LL 3
#define KK 100

// ws float layout
#define WS_PHI     0      // 3 layers * 100 float2 pairs (c, dc) = 600 floats
#define WS_CAP     600    // same for Phi spline
#define WS_INMIN   1200
#define WS_INMAX   1201
#define WS_USCALE  1202   // 99/(in_max-in_min)
#define WS_OUTMIN  1203
#define WS_OUTSPAN 1204
#define WS_CMIN    1205   // +l
#define WS_INVDEN  1208   // +l  1/(cmax-cmin+1e-8)
#define WS_OBEGIN  1211   // int, +l : first o NOT saturated-low
#define WS_OEND    1214   // int, +l : first o saturated-high

__device__ __forceinline__ float fract_pos(float x) {
#if __has_builtin(__builtin_amdgcn_fractf)
  return __builtin_amdgcn_fractf(x);
#else
  return x - floorf(x);
#endif
}

__device__ __forceinline__ float med3f(float x, float lo, float hi) {
#if __has_builtin(__builtin_amdgcn_fmed3f)
  return __builtin_amdgcn_fmed3f(x, lo, hi);
#else
  return fminf(fmaxf(x, lo), hi);
#endif
}

// ---------------- prep: spline pair tables, cmin/cmax, saturation cuts ----------------
__global__ __launch_bounds__(64) void prep_kernel(
    const float* __restrict__ lambdas,
    const float* __restrict__ phi_log_inc,
    const float* __restrict__ Phi_coeffs,
    const float* __restrict__ dc, const float* __restrict__ dr,
    const float* __restrict__ cc, const float* __restrict__ cr,
    float* __restrict__ ws)
{
  const int l = blockIdx.x;   // one block per layer (grid = 3)
  const int t = threadIdx.x;  // 64 threads = 1 wave
  __shared__ float scum[104];

  const float in_min  = dc[0] - dr[0];
  const float in_max  = dc[0] + dr[0];
  const float out_min = cc[0] - cr[0];
  const float out_max = cc[0] + cr[0];
  if (l == 0 && t == 0) {
    ws[WS_INMIN]   = in_min;
    ws[WS_INMAX]   = in_max;
    ws[WS_USCALE]  = 99.0f / (in_max - in_min);
    ws[WS_OUTMIN]  = out_min;
    ws[WS_OUTSPAN] = out_max - out_min;
  }

  // softplus increments + inclusive scan of 100 values (chunk 64 + chunk 36)
  float a = log1pf(expf(phi_log_inc[l*KK + t]));
  #pragma unroll
  for (int d = 1; d < 64; d <<= 1) { float n = __shfl_up(a, d, 64); if (t >= d) a += n; }
  const float totA = __shfl(a, 63, 64);
  float b = (t < 36) ? log1pf(expf(phi_log_inc[l*KK + 64 + t])) : 0.0f;
  #pragma unroll
  for (int d = 1; d < 64; d <<= 1) { float n = __shfl_up(b, d, 64); if (t >= d) b += n; }
  b += totA;
  scum[t] = a;
  if (t < 36) scum[64 + t] = b;
  __syncthreads();
  const float inv = 1.0f / (scum[99] + 1e-8f);

  // phi pairs: entry j = (coef[j], coef[j+1]-coef[j]); entry 99 = (coef[99], 0)
  {
    float c0 = scum[t] * inv;
    float c1 = scum[t + 1] * inv;          // t<=63 -> scum[64] valid
    ws[WS_PHI + l*200 + 2*t]     = c0;
    ws[WS_PHI + l*200 + 2*t + 1] = c1 - c0;
    if (t < 36) {
      int j = 64 + t;
      float d0 = scum[j] * inv;
      float d1 = (j < 99) ? scum[j + 1] * inv - d0 : 0.0f;
      ws[WS_PHI + l*200 + 2*j]     = d0;
      ws[WS_PHI + l*200 + 2*j + 1] = d1;
    }
  }

  // Phi pairs + cmin/cmax
  float C0  = Phi_coeffs[l*KK + t];
  float C64 = (t < 36) ? Phi_coeffs[l*KK + 64 + t] : C0;
  float cmn = fminf(C0, C64), cmx = fmaxf(C0, C64);
  #pragma unroll
  for (int d = 32; d; d >>= 1) {
    cmn = fminf(cmn, __shfl_xor(cmn, d, 64));
    cmx = fmaxf(cmx, __shfl_xor(cmx, d, 64));
  }
  {
    float n1 = Phi_coeffs[l*KK + t + 1];   // t<=63 -> idx 64 valid
    ws[WS_CAP + l*200 + 2*t]     = C0;
    ws[WS_CAP + l*200 + 2*t + 1] = n1 - C0;
    if (t < 36) {
      int j = 64 + t;
      float p0 = Phi_coeffs[l*KK + j];
      float p1 = (j < 99) ? Phi_coeffs[l*KK + j + 1] - p0 : 0.0f;
      ws[WS_CAP + l*200 + 2*j]     = p0;
      ws[WS_CAP + l*200 + 2*j + 1] = p1;
    }
  }

  // lambda negative/positive sums -> saturation cuts.
  // phi(.) in [0,1] always (normalized positive cumsum), so
  //   s = sum_i lam_i*phi + o  in  [o + neg_sum, o + pos_sum].
  float ns = 0.f, ps = 0.f;
  #pragma unroll
  for (int k = 0; k < 8; ++k) {
    float lv = lambdas[l*DD + t + 64*k];
    ns += fminf(lv, 0.f);
    ps += fmaxf(lv, 0.f);
  }
  #pragma unroll
  for (int d = 32; d; d >>= 1) {
    ns += __shfl_xor(ns, d, 64);
    ps += __shfl_xor(ps, d, 64);
  }
  if (t == 0) {
    ws[WS_CMIN + l]   = cmn;
    ws[WS_INVDEN + l] = 1.0f / (cmx - cmn + 1e-8f);
    float T_lo = in_min - ps;   // o <= T_lo  => s <= in_min (clamps low)
    float T_hi = in_max - ns;   // o >= T_hi  => s >= in_max (clamps high)
    int ob = (int)floorf(T_lo) + 1;
    if (ob < 0) ob = 0; if (ob > DD) ob = DD;
    int oe = (int)ceilf(T_hi);
    if (oe < ob) oe = ob; if (oe > DD) oe = DD;
    ((int*)ws)[WS_OBEGIN + l] = ob;
    ((int*)ws)[WS_OEND + l]   = oe;
  }
}

// ---------------- main: whole 3-layer network, one block per batch sample ----------------
__device__ __forceinline__ float phistep(float h, float lam, float eo99,
                                         const float2* __restrict__ sphi, float acc)
{
  // clip(h + eta*o, 0, 1) * 99  ==  med3(99*h + 99*eta*o, 0, 99)
  float xs = med3f(fmaf(h, 99.0f, eo99), 0.0f, 99.0f);
  int   j  = (int)xs;                 // xs in [0,99]; pair[99]=(c99,0) handles xs==99
  float t  = fract_pos(xs);
  float2 p = sphi[j];
  return fmaf(lam, fmaf(t, p.y, p.x), acc);
}

__global__ __launch_bounds__(512) void sprecher_kernel(
    const float* __restrict__ x,
    const float* __restrict__ lambdas,
    const float* __restrict__ eta,
    const float* __restrict__ res_w,
    const float* __restrict__ oscale,
    const float* __restrict__ ws,
    float* __restrict__ out)
{
  __shared__ __align__(16) float2 hl[DD];   // (h_i, lambda_i)
  __shared__ float2 sphi[KK];
  __shared__ float2 scap[KK];
  __shared__ float  sarr[DD];               // heavy s partial sums
  __shared__ float  red[8];

  const int tid  = threadIdx.x;
  const int b    = blockIdx.x;
  const int lane = tid & 63;
  const int wave = tid >> 6;

  const float in_min   = ws[WS_INMIN];
  const float in_max   = ws[WS_INMAX];
  const float uscale   = ws[WS_USCALE];
  const float out_min  = ws[WS_OUTMIN];
  const float out_span = ws[WS_OUTSPAN];

  float hval = x[b*DD + tid];   // this thread's h[b, tid]

  for (int l = 0; l < LL; ++l) {
    __syncthreads();  // prev-layer readers done before restaging
    hl[tid] = make_float2(hval, lambdas[l*DD + tid]);
    if (tid < KK)                          sphi[tid]       = ((const float2*)(ws + WS_PHI))[l*KK + tid];
    else if (tid >= 128 && tid < 128 + KK) scap[tid - 128] = ((const float2*)(ws + WS_CAP))[l*KK + (tid - 128)];
    __syncthreads();

    const float eta99  = 99.0f * eta[l];
    const float cmin   = ws[WS_CMIN + l];
    const float invden = ws[WS_INVDEN + l];
    const float rw     = res_w[l];
    const int   ob     = ((const int*)ws)[WS_OBEGIN + l];
    const int   oe     = ((const int*)ws)[WS_OEND + l];
    const int   nh     = oe - ob;

    // ---- heavy phase: only non-saturated o's need the i-loop.
    // 8 waves round-robin over heavy o's; each wave: 64 lanes x 8 i-elements.
    const float4* hl4 = (const float4*)hl;
    for (int hidx = wave; hidx < nh; hidx += 8) {
      const int   o    = ob + hidx;
      const float eo99 = eta99 * (float)o;
      float acc0 = 0.f, acc1 = 0.f;
      const int base = lane * 4;
      #pragma unroll
      for (int uu = 0; uu < 4; ++uu) {
        float4 v = hl4[base + uu];   // (h[8L+2u], lam, h[8L+2u+1], lam)
        acc0 = phistep(v.x, v.y, eo99, sphi, acc0);
        acc1 = phistep(v.z, v.w, eo99, sphi, acc1);
      }
      float acc = acc0 + acc1;
      #pragma unroll
      for (int d = 32; d; d >>= 1) acc += __shfl_xor(acc, d, 64);
      if (lane == 0) sarr[hidx] = acc;
    }
    __syncthreads();

    // ---- epilogue: one thread per o
    const int o = tid;
    float s;
    if (o < ob)       s = in_min;                     // guaranteed s <= in_min
    else if (o >= oe) s = in_max;                     // guaranteed s >= in_max
    else              s = sarr[o - ob] + (float)o;

    float sc  = fminf(fmaxf(s, in_min), in_max);
    float uq  = fminf((sc - in_min) * uscale, 99.0f);
    int   j   = (int)uq;
    float t2  = fract_pos(uq);
    float2 P  = scap[j];
    float raw = fmaf(t2, P.y, P.x);
    float rn  = med3f((raw - cmin) * invden, 0.0f, 1.0f);
    float act = fmaf(out_span, rn, out_min);
    hval = fmaf(rw, hval, act);
  }

  // final block: sum over o, scale, write out[b]
  float v = hval;
  #pragma unroll
  for (int d = 32; d; d >>= 1) v += __shfl_xor(v, d, 64);
  if (lane == 0) red[wave] = v;
  __syncthreads();
  if (tid == 0) {
    float tot = 0.f;
    #pragma unroll
    for (int w = 0; w < 8; ++w) tot += red[w];
    out[b] = tot * oscale[0];
  }
}

extern "C" void kernel_launch(void* const* d_in, const int* in_sizes, int n_in,
                              void* d_out, int out_size, void* d_ws, size_t ws_size,
                              hipStream_t stream) {
  const float* x           = (const float*)d_in[0];
  const float* lambdas     = (const float*)d_in[1];
  const float* eta         = (const float*)d_in[2];
  const float* phi_log_inc = (const float*)d_in[3];
  const float* Phi_coeffs  = (const float*)d_in[4];
  const float* dc          = (const float*)d_in[5];
  const float* dr          = (const float*)d_in[6];
  const float* cc          = (const float*)d_in[7];
  const float* cr          = (const float*)d_in[8];
  const float* res_w       = (const float*)d_in[9];
  const float* oscale      = (const float*)d_in[10];
  float*       out         = (float*)d_out;
  float*       ws          = (float*)d_ws;

  prep_kernel<<<3, 64, 0, stream>>>(lambdas, phi_log_inc, Phi_coeffs, dc, dr, cc, cr, ws);
  sprecher_kernel<<<512, 512, 0, stream>>>(x, lambdas, eta, res_w, oscale, ws, out);
}

// Round 2
// 81.644 us; speedup vs baseline: 1.0596x; 1.0596x over previous
//
#include <hip/hip_runtime.h>

#define DD 512
#define LL 3
#define KK 100

__device__ __forceinline__ float fract_pos(float x) {
#if __has_builtin(__builtin_amdgcn_fractf)
  return __builtin_amdgcn_fractf(x);
#else
  return x - floorf(x);
#endif
}

__device__ __forceinline__ float med3f(float x, float lo, float hi) {
#if __has_builtin(__builtin_amdgcn_fmed3f)
  return __builtin_amdgcn_fmed3f(x, lo, hi);
#else
  return fminf(fmaxf(x, lo), hi);
#endif
}

// Fully fused: table build + 3-layer network, one block per batch sample.
__global__ __launch_bounds__(512) void sprecher_fused(
    const float* __restrict__ x,
    const float* __restrict__ lambdas,
    const float* __restrict__ eta,
    const float* __restrict__ phi_log_inc,
    const float* __restrict__ Phi_coeffs,
    const float* __restrict__ dc, const float* __restrict__ dr,
    const float* __restrict__ cc, const float* __restrict__ cr,
    const float* __restrict__ res_w,
    const float* __restrict__ oscale,
    float* __restrict__ out)
{
  __shared__ __align__(16) float2 hl[DD];    // (h_i, lambda_i) for current layer
  __shared__ float2 sphi[LL][KK];            // phi pairs (c, dc)  (gather fallback)
  __shared__ float2 scap[LL][KK];            // Phi pairs (c, dc)
  __shared__ float  sarr[DD];                // heavy partial sums
  __shared__ float  wred[8][LL][2];          // per-wave lambda (neg,pos) partials
  __shared__ float  scmin[LL], sinvden[LL];
  __shared__ float2 slin[LL];                // (is_linear_flag, dbar)
  __shared__ int    sob[LL], soe[LL];
  __shared__ float  red[8];

  const int tid  = threadIdx.x;
  const int lane = tid & 63;
  const int wave = tid >> 6;
  const int b    = blockIdx.x;

  const float in_min   = dc[0] - dr[0];
  const float in_max   = dc[0] + dr[0];
  const float out_min  = cc[0] - cr[0];
  const float out_span = (cc[0] + cr[0]) - out_min;
  const float uscale   = 99.0f / (in_max - in_min);

  // preload lambdas (reused for staging) and h
  float lam[LL];
  #pragma unroll
  for (int l = 0; l < LL; ++l) lam[l] = lambdas[l*DD + tid];
  float hval = x[b*DD + tid];

  // ---- lambda neg/pos partial reduce per wave (feeds saturation cuts) ----
  #pragma unroll
  for (int l = 0; l < LL; ++l) {
    float ns = fminf(lam[l], 0.f), ps = fmaxf(lam[l], 0.f);
    #pragma unroll
    for (int d = 32; d; d >>= 1) { ns += __shfl_xor(ns, d, 64); ps += __shfl_xor(ps, d, 64); }
    if (lane == 0) { wred[wave][l][0] = ns; wred[wave][l][1] = ps; }
  }

  // ---- table build: waves 0-2 phi (scan + linearity probe), waves 3-5 Phi ----
  if (wave < 3) {
    const int l = wave;
    auto sp = [](float v) { return fmaxf(v, 0.f) + log1pf(expf(-fabsf(v))); }; // stable softplus
    float a = sp(phi_log_inc[l*KK + lane]);
    #pragma unroll
    for (int d = 1; d < 64; d <<= 1) { float n = __shfl_up(a, d, 64); if (lane >= d) a += n; }
    const float totA = __shfl(a, 63, 64);
    float bb = (lane < 36) ? sp(phi_log_inc[l*KK + 64 + lane]) : 0.0f;
    #pragma unroll
    for (int d = 1; d < 64; d <<= 1) { float n = __shfl_up(bb, d, 64); if (lane >= d) bb += n; }
    bb += totA;
    const float T    = __shfl(bb, 35, 64);       // cum[99]
    const float inv  = 1.0f / (T + 1e-8f);
    const float c64  = __shfl(bb, 0, 64);        // cum[64]
    const float a1   = __shfl_down(a, 1, 64);    // cum[t+1], valid t<63
    const float cA   = a * inv;
    const float nA   = ((lane == 63) ? c64 : a1) * inv;
    sphi[l][lane] = make_float2(cA, nA - cA);
    const float dbar = __shfl(a, 0, 64) * inv;   // c[0] == first increment / T
    bool ok = (fabsf(cA - (float)(lane + 1) * dbar) <= 3e-5f) &&
              (fabsf((nA - cA) - dbar) <= 3e-5f);
    const float b1 = __shfl_down(bb, 1, 64);
    if (lane < 36) {
      const int j = 64 + lane;
      const float cB = bb * inv;
      const float nB = (j < 99) ? b1 * inv : cB;
      sphi[l][j] = make_float2(cB, nB - cB);
      bool okB = (fabsf(cB - (float)(j + 1) * dbar) <= 3e-5f) &&
                 ((j == 99) || fabsf((nB - cB) - dbar) <= 3e-5f);
      ok = ok && okB;
    }
    unsigned long long ball = __ballot(ok);
    if (lane == 0) slin[l] = make_float2((ball == ~0ULL) ? 1.f : 0.f, dbar);
  } else if (wave < 6) {
    const int l = wave - 3;
    const float C0  = Phi_coeffs[l*KK + lane];
    const float C64 = (lane < 36) ? Phi_coeffs[l*KK + 64 + lane] : C0;
    float cmn = fminf(C0, C64), cmx = fmaxf(C0, C64);
    #pragma unroll
    for (int d = 32; d; d >>= 1) {
      cmn = fminf(cmn, __shfl_xor(cmn, d, 64));
      cmx = fmaxf(cmx, __shfl_xor(cmx, d, 64));
    }
    const float n1 = Phi_coeffs[l*KK + lane + 1];     // lane<=63 -> idx 64 valid
    scap[l][lane] = make_float2(C0, n1 - C0);
    if (lane < 36) {
      const int j = 64 + lane;
      const float p1 = (j < 99) ? Phi_coeffs[l*KK + j + 1] - C64 : 0.0f;
      scap[l][j] = make_float2(C64, p1);
    }
    if (lane == 0) { scmin[l] = cmn; sinvden[l] = 1.0f / (cmx - cmn + 1e-8f); }
  }
  __syncthreads();

  // saturation cuts: phi in [0,1] always => s in [o+neg_sum, o+pos_sum]
  if (tid < LL) {
    float ns = 0.f, ps = 0.f;
    for (int w = 0; w < 8; ++w) { ns += wred[w][tid][0]; ps += wred[w][tid][1]; }
    int ob = (int)floorf(in_min - ps) + 1; ob = max(0, min(DD, ob));
    int oe = (int)ceilf(in_max - ns);      oe = max(ob, min(DD, oe));
    sob[tid] = ob; soe[tid] = oe;
  }

  float eta99v[LL], rwv[LL];
  #pragma unroll
  for (int l = 0; l < LL; ++l) { eta99v[l] = 99.0f * eta[l]; rwv[l] = res_w[l]; }

  for (int l = 0; l < LL; ++l) {
    __syncthreads();                 // A: sob visible (l=0) / prev epilogue done
    hl[tid] = make_float2(hval, lam[l]);
    __syncthreads();                 // B
    const int   ob = sob[l], oe = soe[l], nh = oe - ob;
    const float e99 = eta99v[l];
    const float2 li = slin[l];
    const float4* hl4 = (const float4*)hl;

    if (li.x > 0.5f) {
      // linear phi: phi(xs) = (xs+1)*dbar — no gather at all
      const float db = li.y;
      for (int hidx = wave; hidx < nh; hidx += 8) {
        const float eo99 = e99 * (float)(ob + hidx);
        float acc0 = 0.f, acc1 = 0.f;
        #pragma unroll
        for (int uu = 0; uu < 4; ++uu) {
          float4 v = hl4[uu*64 + lane];       // lane-contiguous: conflict-free b128
          float xs0 = med3f(fmaf(v.x, 99.0f, eo99), 0.0f, 99.0f);
          float xs1 = med3f(fmaf(v.z, 99.0f, eo99), 0.0f, 99.0f);
          acc0 = fmaf(v.y, fmaf(xs0, db, db), acc0);
          acc1 = fmaf(v.w, fmaf(xs1, db, db), acc1);
        }
        float acc = acc0 + acc1;
        #pragma unroll
        for (int d = 32; d; d >>= 1) acc += __shfl_xor(acc, d, 64);
        if (lane == 0) sarr[hidx] = acc;
      }
    } else {
      // general path: table gather
      const float2* tp = sphi[l];
      for (int hidx = wave; hidx < nh; hidx += 8) {
        const float eo99 = e99 * (float)(ob + hidx);
        float acc0 = 0.f, acc1 = 0.f;
        #pragma unroll
        for (int uu = 0; uu < 4; ++uu) {
          float4 v = hl4[uu*64 + lane];
          { float xs = med3f(fmaf(v.x, 99.0f, eo99), 0.0f, 99.0f);
            int j = (int)xs; float t = fract_pos(xs); float2 p = tp[j];
            acc0 = fmaf(v.y, fmaf(t, p.y, p.x), acc0); }
          { float xs = med3f(fmaf(v.z, 99.0f, eo99), 0.0f, 99.0f);
            int j = (int)xs; float t = fract_pos(xs); float2 p = tp[j];
            acc1 = fmaf(v.w, fmaf(t, p.y, p.x), acc1); }
        }
        float acc = acc0 + acc1;
        #pragma unroll
        for (int d = 32; d; d >>= 1) acc += __shfl_xor(acc, d, 64);
        if (lane == 0) sarr[hidx] = acc;
      }
    }
    __syncthreads();                 // C

    // epilogue: one thread per o
    const int o = tid;
    float s = (o < ob) ? in_min : (o >= oe) ? in_max : sarr[o - ob] + (float)o;
    float sc  = fminf(fmaxf(s, in_min), in_max);
    float uq  = fminf((sc - in_min) * uscale, 99.0f);
    int   j   = (int)uq;
    float t2  = fract_pos(uq);
    float2 P  = scap[l][j];
    float raw = fmaf(t2, P.y, P.x);
    float rn  = med3f((raw - scmin[l]) * sinvden[l], 0.0f, 1.0f);
    hval = fmaf(rwv[l], hval, fmaf(out_span, rn, out_min));
  }

  // final: sum over o, scale, write out[b]
  float v = hval;
  #pragma unroll
  for (int d = 32; d; d >>= 1) v += __shfl_xor(v, d, 64);
  if (lane == 0) red[wave] = v;
  __syncthreads();
  if (tid == 0) {
    float tot = 0.f;
    for (int w = 0; w < 8; ++w) tot += red[w];
    out[b] = tot * oscale[0];
  }
}

extern "C" void kernel_launch(void* const* d_in, const int* in_sizes, int n_in,
                              void* d_out, int out_size, void* d_ws, size_t ws_size,
                              hipStream_t stream) {
  const float* x           = (const float*)d_in[0];
  const float* lambdas     = (const float*)d_in[1];
  const float* eta         = (const float*)d_in[2];
  const float* phi_log_inc = (const float*)d_in[3];
  const float* Phi_coeffs  = (const float*)d_in[4];
  const float* dc          = (const float*)d_in[5];
  const float* dr          = (const float*)d_in[6];
  const float* cc          = (const float*)d_in[7];
  const float* cr          = (const float*)d_in[8];
  const float* res_w       = (const float*)d_in[9];
  const float* oscale      = (const float*)d_in[10];
  float*       out         = (float*)d_out;

  sprecher_fused<<<512, 512, 0, stream>>>(x, lambdas, eta, phi_log_inc, Phi_coeffs,
                                          dc, dr, cc, cr, res_w, oscale, out);
}